// Round 7
// baseline (183.439 us; speedup 1.0000x reference)
//
#include <hip/hip_runtime.h>

#define VOCAB 100000
#define EMBED 128
#define MAX_PATH 20
#define BATCH 32768
#define WPB 4                     // waves per block (block = 256 threads)
#define NCHUNK 5                  // 20 nodes / 4 groups
#define NBLK (BATCH / WPB * NCHUNK)   // 40960 blocks

// R7: flattened node-parallel mapping. One wave = one (batch, 4-node chunk):
// grid is 5x wider, each wave's serial chain is the irreducible 3 memory
// rounds (c/t -> h+meta -> iv gather) instead of R5's 3 + 5 compiler-
// serialized gather rounds. Only 2 iv-gather instructions per wave -> the
// compiler has nothing to sink (R5 post-mortem: VGPR=32 showed phase-1
// loads were serialized regardless of __launch_bounds__ budget).
// Layout rule kept from R4/R5: each vmem instruction is 256B-contiguous per
// 16-lane group (8 cache lines per wave-instr).
// Chunk-major block mapping (bid/5 = batch-quad, bid%5 = chunk) so the 5
// blocks sharing the same h rows are dispatch-adjacent -> L2-warm re-reads.
// mask == |code| (codes +/-1 valid, 0 pad; padded path ids 0 -> row 0 hot).
// No LDS staging (R6: 40KB/block -> 26% occupancy), no device-scope fences
// (R3: 8x regression).
__global__ __launch_bounds__(256) void hs_loss_kernel(
    const int* __restrict__ center, const int* __restrict__ target,
    const float* __restrict__ in_emb, const float* __restrict__ inner_vec,
    const int* __restrict__ paths, const float* __restrict__ codes,
    float* __restrict__ partials)
{
    const int bid  = blockIdx.x;
    const int x    = bid / NCHUNK;        // batch-quad (scalar magic-mul)
    const int k    = bid - NCHUNK * x;    // chunk 0..4
    const int wave = threadIdx.x >> 6;
    const int lane = threadIdx.x & 63;
    const int g    = lane >> 4;           // group 0..3
    const int gl   = lane & 15;           // lane within group
    const int b    = x * WPB + wave;

    // round 0: batch indices (uniform per wave)
    const int c = center[b];
    const int t = target[b];

    // round 1: h fragment (256B-contiguous per instr) + this group's meta
    const float4* hp = (const float4*)(in_emb + (size_t)c * EMBED);
    const float4 h0 = hp[gl];
    const float4 h1 = hp[gl + 16];
    const int   node = k * 4 + g;         // 0..19
    const int   idx  = t * MAX_PATH + node;
    const int   p    = paths[idx];
    const float cd   = codes[idx];

    // round 2: iv gather — 2 instructions, 4 rows each 256B-contiguous
    const float4* ivp = (const float4*)(inner_vec + (size_t)p * EMBED);
    const float4 a0 = ivp[gl];
    const float4 a1 = ivp[gl + 16];

    // math
    float d = h0.x * a0.x;
    d = fmaf(h0.y, a0.y, d);
    d = fmaf(h0.z, a0.z, d);
    d = fmaf(h0.w, a0.w, d);
    float e = h1.x * a1.x;
    e = fmaf(h1.y, a1.y, e);
    e = fmaf(h1.z, a1.z, e);
    e = fmaf(h1.w, a1.w, e);
    d += e;
    d += __shfl_xor(d, 1, 64);
    d += __shfl_xor(d, 2, 64);
    d += __shfl_xor(d, 4, 64);
    d += __shfl_xor(d, 8, 64);
    const float xx = cd * d;
    const float ls = fminf(xx, 0.f) - __logf(1.f + __expf(-fabsf(xx)));
    float acc = fabsf(cd) * ls;           // |code| == mask (0 on padding)

    // sum the 4 groups' contributions
    acc += __shfl_xor(acc, 16, 64);
    acc += __shfl_xor(acc, 32, 64);

    __shared__ float ws[WPB];
    if (lane == 0) ws[wave] = -acc;
    __syncthreads();
    if (threadIdx.x == 0) {
        partials[bid] = ws[0] + ws[1] + ws[2] + ws[3];
    }
}

__global__ __launch_bounds__(256) void hs_reduce_kernel(
    const float* __restrict__ partials, float* __restrict__ out)
{
    const float4* p4 = (const float4*)partials;     // NBLK/4 = 10240 float4
    float s = 0.f;
    #pragma unroll
    for (int i = 0; i < NBLK / 4 / 256; ++i) {      // 40 per thread
        const float4 v = p4[i * 256 + threadIdx.x];
        s += (v.x + v.y) + (v.z + v.w);
    }
    #pragma unroll
    for (int off = 32; off; off >>= 1) s += __shfl_xor(s, off, 64);
    __shared__ float ws[4];
    const int wave = threadIdx.x >> 6;
    const int lane = threadIdx.x & 63;
    if (lane == 0) ws[wave] = s;
    __syncthreads();
    if (threadIdx.x == 0) {
        out[0] = (ws[0] + ws[1] + ws[2] + ws[3]) / (float)BATCH;
    }
}

extern "C" void kernel_launch(void* const* d_in, const int* in_sizes, int n_in,
                              void* d_out, int out_size, void* d_ws, size_t ws_size,
                              hipStream_t stream) {
    const int*   center    = (const int*)d_in[0];
    const int*   target    = (const int*)d_in[1];
    const float* in_emb    = (const float*)d_in[2];
    const float* inner_vec = (const float*)d_in[3];
    const int*   paths     = (const int*)d_in[4];
    const float* codes     = (const float*)d_in[5];
    // d_in[6] (masks) intentionally unused: mask == |code|
    float* out = (float*)d_out;
    float* partials = (float*)d_ws;   // 40960 floats = 160 KB scratch

    hs_loss_kernel<<<NBLK, 256, 0, stream>>>(
        center, target, in_emb, inner_vec, paths, codes, partials);
    hs_reduce_kernel<<<1, 256, 0, stream>>>(partials, out);
}

// Round 8
// 157.243 us; speedup vs baseline: 1.1666x; 1.1666x over previous
//
#include <hip/hip_runtime.h>

#define VOCAB 100000
#define EMBED 128
#define MAX_PATH 20
#define BATCH 32768
#define WPB 4                    // waves per block (block = 256 threads)
#define NBLOCKS (BATCH / WPB)    // 8192

// R8: hybrid register + async-LDS gather staging, per-wave sync only.
//  - chunks 0,1 -> register gathers (compiler keeps ~2 in flight; R5 evidence)
//  - chunks 2,3,4 -> global_load_lds (un-sinkable, 0 VGPR; R6 evidence)
//  - per-wave s_waitcnt vmcnt(0) instead of __syncthreads: each wave's LDS
//    region is private, so no block-wide load-drain coupling (R6 killer #1)
//  - 6 KB LDS/wave -> 24 KB/block -> 6 blocks/CU = 24 waves/CU (R6 killer #2
//    was 40 KB -> 3 blocks/CU)
//  - chunks 3/4 skipped wave-uniformly when fully padded (P=38%/69%):
//    ballot on codes, known right after the meta round, branch precedes
//    issue -> no serialization. Padded partial chunks still gather row 0
//    (L1-hot). mask == |code| -> masks input unused.
// Layout: every vmem instr is 256B-contiguous per 16-lane group; LDS stage
// obeys dest = uniform base + lane*16 (m104/m108), readback contiguous.
// No device-scope fences (R3: 8x regression).
__global__ __launch_bounds__(256, 6) void hs_loss_kernel(
    const int* __restrict__ center, const int* __restrict__ target,
    const float* __restrict__ in_emb, const float* __restrict__ inner_vec,
    const int* __restrict__ paths, const float* __restrict__ codes,
    float* __restrict__ partials)
{
    __shared__ float4 lds_buf[WPB * 384];   // 3 chunks x 2 KB per wave
    __shared__ float  ws[WPB];

    const int wave = threadIdx.x >> 6;
    const int lane = threadIdx.x & 63;
    const int g    = lane >> 4;   // group 0..3
    const int gl   = lane & 15;   // lane within group
    const int b = blockIdx.x * WPB + wave;

    const int c = center[b];
    const int t = target[b];

    // h fragment (reused 5x): 256B-contiguous per instruction
    const float4* hp = (const float4*)(in_emb + (size_t)c * EMBED);
    const float4 h0 = hp[gl];
    const float4 h1 = hp[gl + 16];

    // Group g's 5 (path, code) pairs: nodes g, g+4, ..., g+16
    const int base = t * MAX_PATH + g;
    int   p[5];
    float cd[5];
    #pragma unroll
    for (int j = 0; j < 5; ++j) {
        p[j]  = paths[base + 4 * j];
        cd[j] = codes[base + 4 * j];
    }
    // wave-uniform chunk validity (all 4 groups share one path length)
    const bool do3 = __ballot(cd[3] != 0.f) != 0ull;
    const bool do4 = __ballot(cd[4] != 0.f) != 0ull;

    // register gathers: chunks 0,1
    const float4* v0 = (const float4*)(inner_vec + (size_t)p[0] * EMBED);
    const float4 r00 = v0[gl], r01 = v0[gl + 16];
    const float4* v1 = (const float4*)(inner_vec + (size_t)p[1] * EMBED);
    const float4 r10 = v1[gl], r11 = v1[gl + 16];

    // async LDS stages: chunks 2,3,4 (two 1024B instrs each)
    float4* myl = lds_buf + wave * 384;
    {
        const float* src = inner_vec + (size_t)p[2] * EMBED + 4 * gl;
        __builtin_amdgcn_global_load_lds(
            (const __attribute__((address_space(1))) unsigned int*)(src),
            (__attribute__((address_space(3))) unsigned int*)(myl),
            16, 0, 0);
        __builtin_amdgcn_global_load_lds(
            (const __attribute__((address_space(1))) unsigned int*)(src + 64),
            (__attribute__((address_space(3))) unsigned int*)(myl + 64),
            16, 0, 0);
    }
    if (do3) {
        const float* src = inner_vec + (size_t)p[3] * EMBED + 4 * gl;
        __builtin_amdgcn_global_load_lds(
            (const __attribute__((address_space(1))) unsigned int*)(src),
            (__attribute__((address_space(3))) unsigned int*)(myl + 128),
            16, 0, 0);
        __builtin_amdgcn_global_load_lds(
            (const __attribute__((address_space(1))) unsigned int*)(src + 64),
            (__attribute__((address_space(3))) unsigned int*)(myl + 192),
            16, 0, 0);
    }
    if (do4) {
        const float* src = inner_vec + (size_t)p[4] * EMBED + 4 * gl;
        __builtin_amdgcn_global_load_lds(
            (const __attribute__((address_space(1))) unsigned int*)(src),
            (__attribute__((address_space(3))) unsigned int*)(myl + 256),
            16, 0, 0);
        __builtin_amdgcn_global_load_lds(
            (const __attribute__((address_space(1))) unsigned int*)(src + 64),
            (__attribute__((address_space(3))) unsigned int*)(myl + 320),
            16, 0, 0);
    }

    float acc = 0.f;
    // ---- chunks 0,1 from registers (compiler inserts partial vmcnt waits)
    #pragma unroll
    for (int j = 0; j < 2; ++j) {
        const float4 a0 = (j == 0) ? r00 : r10;
        const float4 a1 = (j == 0) ? r01 : r11;
        float d = h0.x * a0.x;
        d = fmaf(h0.y, a0.y, d);
        d = fmaf(h0.z, a0.z, d);
        d = fmaf(h0.w, a0.w, d);
        float e = h1.x * a1.x;
        e = fmaf(h1.y, a1.y, e);
        e = fmaf(h1.z, a1.z, e);
        e = fmaf(h1.w, a1.w, e);
        d += e;
        d += __shfl_xor(d, 1, 64);
        d += __shfl_xor(d, 2, 64);
        d += __shfl_xor(d, 4, 64);
        d += __shfl_xor(d, 8, 64);
        const float x  = cd[j] * d;
        const float ls = fminf(x, 0.f) - __logf(1.f + __expf(-fabsf(x)));
        acc = fmaf(fabsf(cd[j]), ls, acc);
    }

    // ---- per-wave drain of my LDS stages (NOT a block barrier)
    __builtin_amdgcn_s_waitcnt(0xF70);      // vmcnt(0), lgkm/exp unconstrained
    __builtin_amdgcn_sched_barrier(0);      // pin: no ds_read hoisted above

    // ---- chunks 2,3,4 from LDS (contiguous ds_read_b128, conflict-free)
    #pragma unroll
    for (int j = 2; j < 5; ++j) {
        if (j == 3 && !do3) continue;       // wave-uniform skip (LDS garbage)
        if (j == 4 && !do4) continue;
        const float4 a0 = myl[(j - 2) * 128 + lane];
        const float4 a1 = myl[(j - 2) * 128 + 64 + lane];
        float d = h0.x * a0.x;
        d = fmaf(h0.y, a0.y, d);
        d = fmaf(h0.z, a0.z, d);
        d = fmaf(h0.w, a0.w, d);
        float e = h1.x * a1.x;
        e = fmaf(h1.y, a1.y, e);
        e = fmaf(h1.z, a1.z, e);
        e = fmaf(h1.w, a1.w, e);
        d += e;
        d += __shfl_xor(d, 1, 64);
        d += __shfl_xor(d, 2, 64);
        d += __shfl_xor(d, 4, 64);
        d += __shfl_xor(d, 8, 64);
        const float x  = cd[j] * d;
        const float ls = fminf(x, 0.f) - __logf(1.f + __expf(-fabsf(x)));
        acc = fmaf(fabsf(cd[j]), ls, acc);
    }

    // sum across the 4 groups
    acc += __shfl_xor(acc, 16, 64);
    acc += __shfl_xor(acc, 32, 64);

    if (lane == 0) ws[wave] = -acc;
    __syncthreads();
    if (threadIdx.x == 0) {
        partials[blockIdx.x] = ws[0] + ws[1] + ws[2] + ws[3];
    }
}

__global__ __launch_bounds__(256) void hs_reduce_kernel(
    const float* __restrict__ partials, float* __restrict__ out)
{
    const float4* p4 = (const float4*)partials;     // 2048 float4
    float s = 0.f;
    #pragma unroll
    for (int i = 0; i < NBLOCKS / 4 / 256; ++i) {
        const float4 v = p4[i * 256 + threadIdx.x];
        s += (v.x + v.y) + (v.z + v.w);
    }
    #pragma unroll
    for (int off = 32; off; off >>= 1) s += __shfl_xor(s, off, 64);
    __shared__ float ws[4];
    const int wave = threadIdx.x >> 6;
    const int lane = threadIdx.x & 63;
    if (lane == 0) ws[wave] = s;
    __syncthreads();
    if (threadIdx.x == 0) {
        out[0] = (ws[0] + ws[1] + ws[2] + ws[3]) / (float)BATCH;
    }
}

extern "C" void kernel_launch(void* const* d_in, const int* in_sizes, int n_in,
                              void* d_out, int out_size, void* d_ws, size_t ws_size,
                              hipStream_t stream) {
    const int*   center    = (const int*)d_in[0];
    const int*   target    = (const int*)d_in[1];
    const float* in_emb    = (const float*)d_in[2];
    const float* inner_vec = (const float*)d_in[3];
    const int*   paths     = (const int*)d_in[4];
    const float* codes     = (const float*)d_in[5];
    // d_in[6] (masks) intentionally unused: mask == |code|
    float* out = (float*)d_out;
    float* partials = (float*)d_ws;   // 8192 floats = 32 KB scratch

    hs_loss_kernel<<<NBLOCKS, 256, 0, stream>>>(
        center, target, in_emb, inner_vec, paths, codes, partials);
    hs_reduce_kernel<<<1, 256, 0, stream>>>(partials, out);
}